// Round 1
// baseline (270.723 us; speedup 1.0000x reference)
//
#include <hip/hip_runtime.h>
#include <hip/hip_bf16.h>

typedef __attribute__((ext_vector_type(8))) short bf16x8;
typedef __attribute__((ext_vector_type(4))) float f32x4;

#define NTOK   2048
#define NEXP   16
#define NF     512
#define NH     1024
#define NCOUT  512
#define NPAIR  8192   // NTOK * 4

__device__ __forceinline__ void gload16_lds(const __hip_bfloat16* g, __hip_bfloat16* l) {
  __builtin_amdgcn_global_load_lds((const __attribute__((address_space(1))) void*)g,
                                   (__attribute__((address_space(3))) void*)l, 16, 0, 0);
}

// ---------------- router: mu/var -> tilde -> softmax -> top4 ----------------
__global__ __launch_bounds__(256) void router_kernel(
    const float* __restrict__ h, const float* __restrict__ W_mu,
    const float* __restrict__ b_mu, const float* __restrict__ W_logvar,
    const float* __restrict__ b_logvar,
    int* __restrict__ topk_idx, float* __restrict__ topk_w, int* __restrict__ counts)
{
  __shared__ float hs[NF], hs2[NF];
  __shared__ float smu[NEXP], svar[NEXP];
  const int b = blockIdx.x, tid = threadIdx.x;
  for (int i = tid; i < NF; i += 256) {
    float v = h[(size_t)b * NF + i];
    hs[i] = v; hs2[i] = v * v;
  }
  __syncthreads();
  const int e = tid >> 4, l = tid & 15;
  float mu = 0.f, var = 0.f;
  for (int i = l; i < NF; i += 16) {
    mu  += hs[i]  * W_mu[e * NF + i];
    var += hs2[i] * expf(W_logvar[e * NF + i]);
  }
#pragma unroll
  for (int o = 1; o < 16; o <<= 1) { mu += __shfl_xor(mu, o); var += __shfl_xor(var, o); }
  if (l == 0) { smu[e] = mu + b_mu[e]; svar[e] = var + expf(b_logvar[e]); }
  __syncthreads();
  if (tid == 0) {
    float t[NEXP];
    float mx = -1e30f;
    for (int i = 0; i < NEXP; ++i) {
      float v = fmaxf(svar[i], 1e-12f);
      float ti = smu[i] / sqrtf(1.0f + 0.39269908169872414f * v);  // pi/8
      t[i] = ti; mx = fmaxf(mx, ti);
    }
    bool used[NEXP] = {};
    int idx[4]; float pw[4]; float wsum = 0.f;
    for (int k = 0; k < 4; ++k) {
      float best = -1e30f; int bi = 0;
      for (int i = 0; i < NEXP; ++i) if (!used[i] && t[i] > best) { best = t[i]; bi = i; }
      used[bi] = true; idx[k] = bi;
      float p = expf(t[bi] - mx); pw[k] = p; wsum += p;
    }
    float inv = 1.0f / fmaxf(wsum, 1e-12f);
    for (int k = 0; k < 4; ++k) {
      topk_idx[b * 4 + k] = idx[k];
      topk_w[b * 4 + k]   = pw[k] * inv;
      atomicAdd(&counts[idx[k]], 1);
    }
  }
}

__global__ void offsets_kernel(const int* __restrict__ counts,
                               int* __restrict__ offsets, int* __restrict__ cursors) {
  if (threadIdx.x == 0) {
    int run = 0;
    for (int e = 0; e < NEXP; ++e) { offsets[e] = run; cursors[e] = run; run += counts[e]; }
  }
}

__global__ __launch_bounds__(256) void scatter_kernel(
    const int* __restrict__ topk_idx, const float* __restrict__ topk_w,
    int* cursors, int* __restrict__ token_of_row, float* __restrict__ row_w)
{
  int t = blockIdx.x * 256 + threadIdx.x;
  if (t >= NPAIR) return;
  int e = topk_idx[t];
  int pos = atomicAdd(&cursors[e], 1);
  token_of_row[pos] = t >> 2;
  row_w[pos] = topk_w[t];
}

// ---------------- conversions ----------------
__global__ __launch_bounds__(256) void convert_h_kernel(
    const float* __restrict__ in, __hip_bfloat16* __restrict__ out, int n4)
{
  int i = blockIdx.x * 256 + threadIdx.x;
  if (i >= n4) return;
  float4 v = ((const float4*)in)[i];
  union { __hip_bfloat16 b[4]; float2 f2; } u;
  u.b[0] = __float2bfloat16(v.x); u.b[1] = __float2bfloat16(v.y);
  u.b[2] = __float2bfloat16(v.z); u.b[3] = __float2bfloat16(v.w);
  *(float2*)(out + (size_t)i * 4) = u.f2;
}

// in: [E][R][C] fp32  ->  out: [E][C][R] bf16
__global__ __launch_bounds__(256) void transpose_convert_kernel(
    const float* __restrict__ in, __hip_bfloat16* __restrict__ out, int R, int C)
{
  __shared__ float tile[32][33];
  const int e = blockIdx.z;
  const int r0 = blockIdx.y * 32, c0 = blockIdx.x * 32;
  const int x = threadIdx.x & 31, y = threadIdx.x >> 5;   // y: 0..7
  const float* ip = in + ((size_t)e * R + r0) * C + c0;
#pragma unroll
  for (int i = 0; i < 4; ++i) tile[y + 8 * i][x] = ip[(size_t)(y + 8 * i) * C + x];
  __syncthreads();
  __hip_bfloat16* op = out + ((size_t)e * C + c0) * R + r0;
#pragma unroll
  for (int i = 0; i < 4; ++i) op[(size_t)(y + 8 * i) * R + x] = __float2bfloat16(tile[x][y + 8 * i]);
}

// ---------------- GEMM1: a = relu(h @ W1 + b1), gathered rows ----------------
__global__ __launch_bounds__(256) void gemm1_kernel(
    const __hip_bfloat16* __restrict__ hb,   // [NTOK, NF]
    const __hip_bfloat16* __restrict__ W1t,  // [E, NH, NF]  (n-major)
    const float* __restrict__ b1,            // [E, NH]
    const int* __restrict__ token_of_row, const int* __restrict__ offsets,
    const int* __restrict__ counts,
    __hip_bfloat16* __restrict__ a_out)      // [NPAIR, NH]
{
  const int e  = blockIdx.z;
  const int m0 = blockIdx.y * 64;
  const int n0 = blockIdx.x * 64;
  const int cnt = counts[e];
  if (m0 >= cnt) return;
  const int off = offsets[e];

  __shared__ __align__(16) __hip_bfloat16 As[2048]; // [g:4][row:64][8]
  __shared__ __align__(16) __hip_bfloat16 Bs[2048];

  const int tid = threadIdx.x;
  const int w = tid >> 6, l = tid & 63;
  const int wm = w >> 1, wn = w & 1;
  const int g = l >> 4, r16 = l & 15;

  int rowA = off + m0 + l; if (rowA > NPAIR - 1) rowA = NPAIR - 1;
  const int tok = token_of_row[rowA];
  const __hip_bfloat16* Ag = hb + (size_t)tok * NF + w * 8;
  const __hip_bfloat16* Bg = W1t + ((size_t)e * NH + n0 + l) * NF + w * 8;
  __hip_bfloat16* Asw = As + w * 512;
  __hip_bfloat16* Bsw = Bs + w * 512;

  f32x4 acc[2][2] = {};

  for (int k0 = 0; k0 < NF; k0 += 32) {
    __syncthreads();
    gload16_lds(Ag + k0, Asw);
    gload16_lds(Bg + k0, Bsw);
    __syncthreads();
    bf16x8 af[2], bq[2];
#pragma unroll
    for (int rr = 0; rr < 2; ++rr)
      af[rr] = *(const bf16x8*)(As + g * 512 + (wm * 32 + rr * 16 + r16) * 8);
#pragma unroll
    for (int nn = 0; nn < 2; ++nn)
      bq[nn] = *(const bf16x8*)(Bs + g * 512 + (wn * 32 + nn * 16 + r16) * 8);
#pragma unroll
    for (int rr = 0; rr < 2; ++rr)
#pragma unroll
      for (int nn = 0; nn < 2; ++nn)
        acc[rr][nn] = __builtin_amdgcn_mfma_f32_16x16x32_bf16(af[rr], bq[nn], acc[rr][nn], 0, 0, 0);
  }

  const int q4 = l >> 4, cl = l & 15;
  const int mmax = cnt - m0;
#pragma unroll
  for (int rr = 0; rr < 2; ++rr) {
#pragma unroll
    for (int nn = 0; nn < 2; ++nn) {
      const int c = n0 + wn * 32 + nn * 16 + cl;
      const float bias = b1[e * NH + c];
#pragma unroll
      for (int q = 0; q < 4; ++q) {
        const int r = wm * 32 + rr * 16 + q4 * 4 + q;
        if (r < mmax) {
          float v = fmaxf(acc[rr][nn][q] + bias, 0.f);
          a_out[(size_t)(off + m0 + r) * NH + c] = __float2bfloat16(v);
        }
      }
    }
  }
}

// ---------------- GEMM2: out += w * (a @ W2 + b2), fused scatter ----------------
__global__ __launch_bounds__(256) void gemm2_kernel(
    const __hip_bfloat16* __restrict__ a_in,  // [NPAIR, NH]
    const __hip_bfloat16* __restrict__ W2t,   // [E, NCOUT, NH] (n-major)
    const float* __restrict__ b2,             // [E, NCOUT]
    const int* __restrict__ token_of_row, const float* __restrict__ row_w,
    const int* __restrict__ offsets, const int* __restrict__ counts,
    float* __restrict__ out)                  // [NTOK, NCOUT]
{
  const int e  = blockIdx.z;
  const int m0 = blockIdx.y * 64;
  const int n0 = blockIdx.x * 64;
  const int cnt = counts[e];
  if (m0 >= cnt) return;
  const int off = offsets[e];

  __shared__ __align__(16) __hip_bfloat16 As[2048];
  __shared__ __align__(16) __hip_bfloat16 Bs[2048];

  const int tid = threadIdx.x;
  const int w = tid >> 6, l = tid & 63;
  const int wm = w >> 1, wn = w & 1;
  const int g = l >> 4, r16 = l & 15;

  int rowA = off + m0 + l; if (rowA > NPAIR - 1) rowA = NPAIR - 1;
  const __hip_bfloat16* Ag = a_in + (size_t)rowA * NH + w * 8;
  const __hip_bfloat16* Bg = W2t + ((size_t)e * NCOUT + n0 + l) * NH + w * 8;
  __hip_bfloat16* Asw = As + w * 512;
  __hip_bfloat16* Bsw = Bs + w * 512;

  f32x4 acc[2][2] = {};

  for (int k0 = 0; k0 < NH; k0 += 32) {
    __syncthreads();
    gload16_lds(Ag + k0, Asw);
    gload16_lds(Bg + k0, Bsw);
    __syncthreads();
    bf16x8 af[2], bq[2];
#pragma unroll
    for (int rr = 0; rr < 2; ++rr)
      af[rr] = *(const bf16x8*)(As + g * 512 + (wm * 32 + rr * 16 + r16) * 8);
#pragma unroll
    for (int nn = 0; nn < 2; ++nn)
      bq[nn] = *(const bf16x8*)(Bs + g * 512 + (wn * 32 + nn * 16 + r16) * 8);
#pragma unroll
    for (int rr = 0; rr < 2; ++rr)
#pragma unroll
      for (int nn = 0; nn < 2; ++nn)
        acc[rr][nn] = __builtin_amdgcn_mfma_f32_16x16x32_bf16(af[rr], bq[nn], acc[rr][nn], 0, 0, 0);
  }

  const int q4 = l >> 4, cl = l & 15;
  const int mmax = cnt - m0;
#pragma unroll
  for (int rr = 0; rr < 2; ++rr) {
#pragma unroll
    for (int nn = 0; nn < 2; ++nn) {
      const int c = n0 + wn * 32 + nn * 16 + cl;
      const float bias = b2[e * NCOUT + c];
#pragma unroll
      for (int q = 0; q < 4; ++q) {
        const int r = wm * 32 + rr * 16 + q4 * 4 + q;
        if (r < mmax) {
          const int grow = off + m0 + r;
          const int tok = token_of_row[grow];
          const float wt = row_w[grow];
          atomicAdd(&out[(size_t)tok * NCOUT + c], wt * (acc[rr][nn][q] + bias));
        }
      }
    }
  }
}

extern "C" void kernel_launch(void* const* d_in, const int* in_sizes, int n_in,
                              void* d_out, int out_size, void* d_ws, size_t ws_size,
                              hipStream_t stream) {
  (void)in_sizes; (void)n_in; (void)ws_size;
  const float* h        = (const float*)d_in[0];
  const float* W_mu     = (const float*)d_in[1];
  const float* b_mu     = (const float*)d_in[2];
  const float* W_logvar = (const float*)d_in[3];
  const float* b_logvar = (const float*)d_in[4];
  const float* W1       = (const float*)d_in[5];
  const float* b1       = (const float*)d_in[6];
  const float* W2       = (const float*)d_in[7];
  const float* b2       = (const float*)d_in[8];
  float* out = (float*)d_out;

  char* p = (char*)d_ws;
  int*   counts   = (int*)p;  p += 16 * 4;
  int*   cursors  = (int*)p;  p += 16 * 4;
  int*   offsets  = (int*)p;  p += 16 * 4;
  p += 16 * 4; // pad to 16B multiple overall
  int*   topk_idx = (int*)p;   p += (size_t)NPAIR * 4;
  float* topk_w   = (float*)p; p += (size_t)NPAIR * 4;
  int*   tok_row  = (int*)p;   p += (size_t)NPAIR * 4;
  float* row_w    = (float*)p; p += (size_t)NPAIR * 4;
  __hip_bfloat16* hb   = (__hip_bfloat16*)p; p += (size_t)NTOK * NF * 2;
  __hip_bfloat16* W1t  = (__hip_bfloat16*)p; p += (size_t)NEXP * NF * NH * 2;
  __hip_bfloat16* W2t  = (__hip_bfloat16*)p; p += (size_t)NEXP * NH * NCOUT * 2;
  __hip_bfloat16* abuf = (__hip_bfloat16*)p; p += (size_t)NPAIR * NH * 2;

  hipMemsetAsync(d_out, 0, (size_t)out_size * 4, stream);
  hipMemsetAsync(counts, 0, 16 * 4, stream);

  router_kernel<<<NTOK, 256, 0, stream>>>(h, W_mu, b_mu, W_logvar, b_logvar,
                                          topk_idx, topk_w, counts);
  offsets_kernel<<<1, 64, 0, stream>>>(counts, offsets, cursors);
  scatter_kernel<<<NPAIR / 256, 256, 0, stream>>>(topk_idx, topk_w, cursors, tok_row, row_w);

  convert_h_kernel<<<(NTOK * NF / 4) / 256, 256, 0, stream>>>(h, hb, NTOK * NF / 4);
  transpose_convert_kernel<<<dim3(NH / 32, NF / 32, NEXP), 256, 0, stream>>>(W1, W1t, NF, NH);
  transpose_convert_kernel<<<dim3(NCOUT / 32, NH / 32, NEXP), 256, 0, stream>>>(W2, W2t, NH, NCOUT);

  gemm1_kernel<<<dim3(NH / 64, NTOK / 64, NEXP), 256, 0, stream>>>(
      hb, W1t, b1, tok_row, offsets, counts, abuf);
  gemm2_kernel<<<dim3(NCOUT / 64, NTOK / 64, NEXP), 256, 0, stream>>>(
      abuf, W2t, b2, tok_row, row_w, offsets, counts, out);
}

// Round 2
// 172.135 us; speedup vs baseline: 1.5727x; 1.5727x over previous
//
#include <hip/hip_runtime.h>
#include <hip/hip_bf16.h>

typedef __attribute__((ext_vector_type(8))) short bf16x8;
typedef __attribute__((ext_vector_type(4))) float f32x4;

#define NTOK   2048
#define NEXP   16
#define NF     512
#define NH     1024
#define NCOUT  512
#define NPAIR  8192   // NTOK * 4

__device__ __forceinline__ void gload16_lds(const __hip_bfloat16* g, __hip_bfloat16* l) {
  __builtin_amdgcn_global_load_lds((const __attribute__((address_space(1))) void*)g,
                                   (__attribute__((address_space(3))) void*)l, 16, 0, 0);
}

// ---------------- precompute exp(W_logvar), exp(b_logvar) ----------------
__global__ __launch_bounds__(256) void precompute_kernel(
    const float* __restrict__ W_logvar, const float* __restrict__ b_logvar,
    float* __restrict__ expW, float* __restrict__ expb)
{
  int i = blockIdx.x * 256 + threadIdx.x;
  if (i < NEXP * NF) expW[i] = expf(W_logvar[i]);
  if (i < NEXP) expb[i] = expf(b_logvar[i]);
}

// ---------------- router: mu/var -> tilde -> top4 + renorm softmax ----------------
// No atomics. Also emits hb (bf16 h) since h is staged in LDS anyway.
__global__ __launch_bounds__(256) void router_kernel(
    const float* __restrict__ h, const float* __restrict__ W_mu,
    const float* __restrict__ b_mu, const float* __restrict__ expW,
    const float* __restrict__ expb,
    int* __restrict__ topk_idx, float* __restrict__ topk_w,
    __hip_bfloat16* __restrict__ hb)
{
  __shared__ __align__(16) float hs[NF], hs2[NF];
  __shared__ float smu[NEXP], svar[NEXP];
  const int b = blockIdx.x, tid = threadIdx.x;
  for (int i = tid; i < NF; i += 256) {
    float v = h[(size_t)b * NF + i];
    hs[i] = v; hs2[i] = v * v;
    hb[(size_t)b * NF + i] = __float2bfloat16(v);
  }
  __syncthreads();
  const int e = tid >> 4, l = tid & 15;
  float mu = 0.f, var = 0.f;
  const float4* wm4 = (const float4*)(W_mu + e * NF);
  const float4* wv4 = (const float4*)(expW + e * NF);
  const float4* h4  = (const float4*)hs;
  const float4* h24 = (const float4*)hs2;
#pragma unroll
  for (int j = 0; j < NF / 64; ++j) {
    int i4 = l + j * 16;
    float4 a = h4[i4],  wa = wm4[i4];
    float4 c = h24[i4], wc = wv4[i4];
    mu  += a.x * wa.x + a.y * wa.y + a.z * wa.z + a.w * wa.w;
    var += c.x * wc.x + c.y * wc.y + c.z * wc.z + c.w * wc.w;
  }
#pragma unroll
  for (int o = 1; o < 16; o <<= 1) { mu += __shfl_xor(mu, o); var += __shfl_xor(var, o); }
  if (l == 0) { smu[e] = mu + b_mu[e]; svar[e] = var + expb[e]; }
  __syncthreads();
  if (tid < 64) {
    float val = -1e30f;
    if (tid < NEXP) {
      float v = fmaxf(svar[tid], 1e-12f);
      val = smu[tid] / sqrtf(1.0f + 0.39269908169872414f * v);  // pi/8
    }
    float mx = 0.f, wsum = 0.f;
    int i0, i1, i2, i3; float p0, p1, p2, p3;
#define TOPK_ROUND(ii, pp, FIRST)                                          \
    {                                                                      \
      float m = val;                                                       \
      m = fmaxf(m, __shfl_xor(m, 1));  m = fmaxf(m, __shfl_xor(m, 2));     \
      m = fmaxf(m, __shfl_xor(m, 4));  m = fmaxf(m, __shfl_xor(m, 8));     \
      m = fmaxf(m, __shfl_xor(m, 16)); m = fmaxf(m, __shfl_xor(m, 32));    \
      unsigned long long bm = __ballot(val == m);                          \
      int bi = (int)__builtin_ctzll(bm);                                   \
      if (FIRST) mx = m;                                                   \
      pp = expf(m - mx); wsum += pp; ii = bi;                              \
      if (tid == bi) val = -1e30f;                                         \
    }
    TOPK_ROUND(i0, p0, 1)
    TOPK_ROUND(i1, p1, 0)
    TOPK_ROUND(i2, p2, 0)
    TOPK_ROUND(i3, p3, 0)
#undef TOPK_ROUND
    if (tid == 0) {
      float inv = 1.0f / fmaxf(wsum, 1e-12f);
      topk_idx[b * 4 + 0] = i0; topk_w[b * 4 + 0] = p0 * inv;
      topk_idx[b * 4 + 1] = i1; topk_w[b * 4 + 1] = p1 * inv;
      topk_idx[b * 4 + 2] = i2; topk_w[b * 4 + 2] = p2 * inv;
      topk_idx[b * 4 + 3] = i3; topk_w[b * 4 + 3] = p3 * inv;
    }
  }
}

// ---------------- per-expert count (no atomics) ----------------
__global__ __launch_bounds__(256) void count_kernel(
    const int* __restrict__ topk_idx, int* __restrict__ counts)
{
  const int e = blockIdx.x;
  int c = 0;
  for (int i = threadIdx.x; i < NPAIR; i += 256) c += (topk_idx[i] == e);
#pragma unroll
  for (int o = 1; o < 64; o <<= 1) c += __shfl_xor(c, o);
  __shared__ int ws[4];
  if ((threadIdx.x & 63) == 0) ws[threadIdx.x >> 6] = c;
  __syncthreads();
  if (threadIdx.x == 0) counts[e] = ws[0] + ws[1] + ws[2] + ws[3];
}

__global__ void offsets_kernel(const int* __restrict__ counts, int* __restrict__ offsets) {
  if (threadIdx.x == 0) {
    int run = 0;
    for (int e = 0; e < NEXP; ++e) { offsets[e] = run; run += counts[e]; }
  }
}

// ---------------- stable scatter (deterministic, no atomics) ----------------
__global__ __launch_bounds__(256) void scatter_kernel(
    const int* __restrict__ topk_idx, const float* __restrict__ topk_w,
    const int* __restrict__ offsets,
    int* __restrict__ token_of_row, float* __restrict__ row_w)
{
  const int e = blockIdx.x;
  __shared__ int wsum[4];
  __shared__ int chunk_base;
  if (threadIdx.x == 0) chunk_base = offsets[e];
  __syncthreads();
  const int wid = threadIdx.x >> 6, lane = threadIdx.x & 63;
  for (int c0 = 0; c0 < NPAIR; c0 += 256) {
    const int t = c0 + threadIdx.x;
    const bool f = (topk_idx[t] == e);
    const unsigned long long m = __ballot(f);
    const int pre = __popcll(m & ((1ull << lane) - 1ull));
    if (lane == 0) wsum[wid] = __popcll(m);
    __syncthreads();
    int wbase = 0;
#pragma unroll
    for (int i = 0; i < 4; ++i) if (i < wid) wbase += wsum[i];
    const int total = wsum[0] + wsum[1] + wsum[2] + wsum[3];
    if (f) {
      const int pos = chunk_base + wbase + pre;
      token_of_row[pos] = t >> 2;
      row_w[pos] = topk_w[t];
    }
    __syncthreads();
    if (threadIdx.x == 0) chunk_base += total;
  }
}

// ---------------- weight transpose+convert: [E][R][C] f32 -> [E][C][R] bf16 ----------------
__global__ __launch_bounds__(256) void transpose_convert_kernel(
    const float* __restrict__ in, __hip_bfloat16* __restrict__ out, int R, int C)
{
  __shared__ float tile[32][33];
  const int e = blockIdx.z;
  const int r0 = blockIdx.y * 32, c0 = blockIdx.x * 32;
  const int x = threadIdx.x & 31, y = threadIdx.x >> 5;   // y: 0..7
  const float* ip = in + ((size_t)e * R + r0) * C + c0;
#pragma unroll
  for (int i = 0; i < 4; ++i) tile[y + 8 * i][x] = ip[(size_t)(y + 8 * i) * C + x];
  __syncthreads();
  __hip_bfloat16* op = out + ((size_t)e * C + c0) * R + r0;
#pragma unroll
  for (int i = 0; i < 4; ++i) op[(size_t)(y + 8 * i) * R + x] = __float2bfloat16(tile[x][y + 8 * i]);
}

// ---------------- GEMM1: a = relu(h @ W1 + b1), gathered rows ----------------
__global__ __launch_bounds__(256) void gemm1_kernel(
    const __hip_bfloat16* __restrict__ hb,   // [NTOK, NF]
    const __hip_bfloat16* __restrict__ W1t,  // [E, NH, NF]  (n-major)
    const float* __restrict__ b1,            // [E, NH]
    const int* __restrict__ token_of_row, const int* __restrict__ offsets,
    const int* __restrict__ counts,
    __hip_bfloat16* __restrict__ a_out)      // [NPAIR, NH]
{
  const int e  = blockIdx.z;
  const int m0 = blockIdx.y * 64;
  const int n0 = blockIdx.x * 64;
  const int cnt = counts[e];
  if (m0 >= cnt) return;
  const int off = offsets[e];

  __shared__ __align__(16) __hip_bfloat16 As[2048]; // [g:4][row:64][8]
  __shared__ __align__(16) __hip_bfloat16 Bs[2048];

  const int tid = threadIdx.x;
  const int w = tid >> 6, l = tid & 63;
  const int wm = w >> 1, wn = w & 1;
  const int g = l >> 4, r16 = l & 15;

  int rowA = off + m0 + l; if (rowA > NPAIR - 1) rowA = NPAIR - 1;
  const int tok = token_of_row[rowA];
  const __hip_bfloat16* Ag = hb + (size_t)tok * NF + w * 8;
  const __hip_bfloat16* Bg = W1t + ((size_t)e * NH + n0 + l) * NF + w * 8;
  __hip_bfloat16* Asw = As + w * 512;
  __hip_bfloat16* Bsw = Bs + w * 512;

  f32x4 acc[2][2] = {};

  for (int k0 = 0; k0 < NF; k0 += 32) {
    __syncthreads();
    gload16_lds(Ag + k0, Asw);
    gload16_lds(Bg + k0, Bsw);
    __syncthreads();
    bf16x8 af[2], bq[2];
#pragma unroll
    for (int rr = 0; rr < 2; ++rr)
      af[rr] = *(const bf16x8*)(As + g * 512 + (wm * 32 + rr * 16 + r16) * 8);
#pragma unroll
    for (int nn = 0; nn < 2; ++nn)
      bq[nn] = *(const bf16x8*)(Bs + g * 512 + (wn * 32 + nn * 16 + r16) * 8);
#pragma unroll
    for (int rr = 0; rr < 2; ++rr)
#pragma unroll
      for (int nn = 0; nn < 2; ++nn)
        acc[rr][nn] = __builtin_amdgcn_mfma_f32_16x16x32_bf16(af[rr], bq[nn], acc[rr][nn], 0, 0, 0);
  }

  const int q4 = l >> 4, cl = l & 15;
  const int mmax = cnt - m0;
#pragma unroll
  for (int rr = 0; rr < 2; ++rr) {
#pragma unroll
    for (int nn = 0; nn < 2; ++nn) {
      const int c = n0 + wn * 32 + nn * 16 + cl;
      const float bias = b1[e * NH + c];
#pragma unroll
      for (int q = 0; q < 4; ++q) {
        const int r = wm * 32 + rr * 16 + q4 * 4 + q;
        if (r < mmax) {
          float v = fmaxf(acc[rr][nn][q] + bias, 0.f);
          a_out[(size_t)(off + m0 + r) * NH + c] = __float2bfloat16(v);
        }
      }
    }
  }
}

// ---------------- GEMM2: out += w * (a @ W2 + b2), fused scatter ----------------
__global__ __launch_bounds__(256) void gemm2_kernel(
    const __hip_bfloat16* __restrict__ a_in,  // [NPAIR, NH]
    const __hip_bfloat16* __restrict__ W2t,   // [E, NCOUT, NH] (n-major)
    const float* __restrict__ b2,             // [E, NCOUT]
    const int* __restrict__ token_of_row, const float* __restrict__ row_w,
    const int* __restrict__ offsets, const int* __restrict__ counts,
    float* __restrict__ out)                  // [NTOK, NCOUT]
{
  const int e  = blockIdx.z;
  const int m0 = blockIdx.y * 64;
  const int n0 = blockIdx.x * 64;
  const int cnt = counts[e];
  if (m0 >= cnt) return;
  const int off = offsets[e];

  __shared__ __align__(16) __hip_bfloat16 As[2048];
  __shared__ __align__(16) __hip_bfloat16 Bs[2048];

  const int tid = threadIdx.x;
  const int w = tid >> 6, l = tid & 63;
  const int wm = w >> 1, wn = w & 1;
  const int g = l >> 4, r16 = l & 15;

  int rowA = off + m0 + l; if (rowA > NPAIR - 1) rowA = NPAIR - 1;
  const __hip_bfloat16* Ag = a_in + (size_t)rowA * NH + w * 8;
  const __hip_bfloat16* Bg = W2t + ((size_t)e * NCOUT + n0 + l) * NH + w * 8;
  __hip_bfloat16* Asw = As + w * 512;
  __hip_bfloat16* Bsw = Bs + w * 512;

  f32x4 acc[2][2] = {};

  for (int k0 = 0; k0 < NH; k0 += 32) {
    __syncthreads();
    gload16_lds(Ag + k0, Asw);
    gload16_lds(Bg + k0, Bsw);
    __syncthreads();
    bf16x8 af[2], bq[2];
#pragma unroll
    for (int rr = 0; rr < 2; ++rr)
      af[rr] = *(const bf16x8*)(As + g * 512 + (wm * 32 + rr * 16 + r16) * 8);
#pragma unroll
    for (int nn = 0; nn < 2; ++nn)
      bq[nn] = *(const bf16x8*)(Bs + g * 512 + (wn * 32 + nn * 16 + r16) * 8);
#pragma unroll
    for (int rr = 0; rr < 2; ++rr)
#pragma unroll
      for (int nn = 0; nn < 2; ++nn)
        acc[rr][nn] = __builtin_amdgcn_mfma_f32_16x16x32_bf16(af[rr], bq[nn], acc[rr][nn], 0, 0, 0);
  }

  const int q4 = l >> 4, cl = l & 15;
  const int mmax = cnt - m0;
#pragma unroll
  for (int rr = 0; rr < 2; ++rr) {
#pragma unroll
    for (int nn = 0; nn < 2; ++nn) {
      const int c = n0 + wn * 32 + nn * 16 + cl;
      const float bias = b2[e * NCOUT + c];
#pragma unroll
      for (int q = 0; q < 4; ++q) {
        const int r = wm * 32 + rr * 16 + q4 * 4 + q;
        if (r < mmax) {
          const int grow = off + m0 + r;
          const int tok = token_of_row[grow];
          const float wt = row_w[grow];
          atomicAdd(&out[(size_t)tok * NCOUT + c], wt * (acc[rr][nn][q] + bias));
        }
      }
    }
  }
}

extern "C" void kernel_launch(void* const* d_in, const int* in_sizes, int n_in,
                              void* d_out, int out_size, void* d_ws, size_t ws_size,
                              hipStream_t stream) {
  (void)in_sizes; (void)n_in; (void)ws_size;
  const float* h        = (const float*)d_in[0];
  const float* W_mu     = (const float*)d_in[1];
  const float* b_mu     = (const float*)d_in[2];
  const float* W_logvar = (const float*)d_in[3];
  const float* b_logvar = (const float*)d_in[4];
  const float* W1       = (const float*)d_in[5];
  const float* b1       = (const float*)d_in[6];
  const float* W2       = (const float*)d_in[7];
  const float* b2       = (const float*)d_in[8];
  float* out = (float*)d_out;

  char* p = (char*)d_ws;
  int*   counts   = (int*)p;   p += 16 * 4;
  int*   offsets  = (int*)p;   p += 16 * 4;
  float* expb     = (float*)p; p += 16 * 4;
  p += 16 * 4; // pad
  float* expW     = (float*)p; p += (size_t)NEXP * NF * 4;
  int*   topk_idx = (int*)p;   p += (size_t)NPAIR * 4;
  float* topk_w   = (float*)p; p += (size_t)NPAIR * 4;
  int*   tok_row  = (int*)p;   p += (size_t)NPAIR * 4;
  float* row_w    = (float*)p; p += (size_t)NPAIR * 4;
  __hip_bfloat16* hb   = (__hip_bfloat16*)p; p += (size_t)NTOK * NF * 2;
  __hip_bfloat16* W1t  = (__hip_bfloat16*)p; p += (size_t)NEXP * NF * NH * 2;
  __hip_bfloat16* W2t  = (__hip_bfloat16*)p; p += (size_t)NEXP * NH * NCOUT * 2;
  __hip_bfloat16* abuf = (__hip_bfloat16*)p; p += (size_t)NPAIR * NH * 2;

  hipMemsetAsync(d_out, 0, (size_t)out_size * 4, stream);

  precompute_kernel<<<(NEXP * NF + 255) / 256, 256, 0, stream>>>(W_logvar, b_logvar, expW, expb);
  router_kernel<<<NTOK, 256, 0, stream>>>(h, W_mu, b_mu, expW, expb, topk_idx, topk_w, hb);
  count_kernel<<<NEXP, 256, 0, stream>>>(topk_idx, counts);
  offsets_kernel<<<1, 64, 0, stream>>>(counts, offsets);
  scatter_kernel<<<NEXP, 256, 0, stream>>>(topk_idx, topk_w, offsets, tok_row, row_w);

  transpose_convert_kernel<<<dim3(NH / 32, NF / 32, NEXP), 256, 0, stream>>>(W1, W1t, NF, NH);
  transpose_convert_kernel<<<dim3(NCOUT / 32, NH / 32, NEXP), 256, 0, stream>>>(W2, W2t, NH, NCOUT);

  gemm1_kernel<<<dim3(NH / 64, NTOK / 64, NEXP), 256, 0, stream>>>(
      hb, W1t, b1, tok_row, offsets, counts, abuf);
  gemm2_kernel<<<dim3(NCOUT / 64, NTOK / 64, NEXP), 256, 0, stream>>>(
      abuf, W2t, b2, tok_row, row_w, offsets, counts, out);
}

// Round 3
// 167.673 us; speedup vs baseline: 1.6146x; 1.0266x over previous
//
#include <hip/hip_runtime.h>
#include <hip/hip_bf16.h>

typedef __attribute__((ext_vector_type(8))) short bf16x8;
typedef __attribute__((ext_vector_type(4))) float f32x4;

#define NTOK   2048
#define NEXP   16
#define NF     512
#define NH     1024
#define NCOUT  512
#define NPAIR  8192   // NTOK * 4

__device__ __forceinline__ void gload16_lds(const __hip_bfloat16* g, __hip_bfloat16* l) {
  __builtin_amdgcn_global_load_lds((const __attribute__((address_space(1))) void*)g,
                                   (__attribute__((address_space(3))) void*)l, 16, 0, 0);
}

// ---------------- precompute exp(W_logvar), exp(b_logvar) ----------------
__global__ __launch_bounds__(256) void precompute_kernel(
    const float* __restrict__ W_logvar, const float* __restrict__ b_logvar,
    float* __restrict__ expW, float* __restrict__ expb)
{
  int i = blockIdx.x * 256 + threadIdx.x;
  if (i < NEXP * NF) expW[i] = expf(W_logvar[i]);
  if (i < NEXP) expb[i] = expf(b_logvar[i]);
}

// ---------------- router: mu/var -> tilde -> top4 + renorm softmax ----------------
__global__ __launch_bounds__(256) void router_kernel(
    const float* __restrict__ h, const float* __restrict__ W_mu,
    const float* __restrict__ b_mu, const float* __restrict__ expW,
    const float* __restrict__ expb,
    int* __restrict__ topk_idx, float* __restrict__ topk_w,
    __hip_bfloat16* __restrict__ hb)
{
  __shared__ __align__(16) float hs[NF], hs2[NF];
  __shared__ float smu[NEXP], svar[NEXP];
  const int b = blockIdx.x, tid = threadIdx.x;
  for (int i = tid; i < NF; i += 256) {
    float v = h[(size_t)b * NF + i];
    hs[i] = v; hs2[i] = v * v;
    hb[(size_t)b * NF + i] = __float2bfloat16(v);
  }
  __syncthreads();
  const int e = tid >> 4, l = tid & 15;
  float mu = 0.f, var = 0.f;
  const float4* wm4 = (const float4*)(W_mu + e * NF);
  const float4* wv4 = (const float4*)(expW + e * NF);
  const float4* h4  = (const float4*)hs;
  const float4* h24 = (const float4*)hs2;
#pragma unroll
  for (int j = 0; j < NF / 64; ++j) {
    int i4 = l + j * 16;
    float4 a = h4[i4],  wa = wm4[i4];
    float4 c = h24[i4], wc = wv4[i4];
    mu  += a.x * wa.x + a.y * wa.y + a.z * wa.z + a.w * wa.w;
    var += c.x * wc.x + c.y * wc.y + c.z * wc.z + c.w * wc.w;
  }
#pragma unroll
  for (int o = 1; o < 16; o <<= 1) { mu += __shfl_xor(mu, o); var += __shfl_xor(var, o); }
  if (l == 0) { smu[e] = mu + b_mu[e]; svar[e] = var + expb[e]; }
  __syncthreads();
  if (tid < 64) {
    float val = -1e30f;
    if (tid < NEXP) {
      float v = fmaxf(svar[tid], 1e-12f);
      val = smu[tid] / sqrtf(1.0f + 0.39269908169872414f * v);  // pi/8
    }
    float mx = 0.f, wsum = 0.f;
    int i0, i1, i2, i3; float p0, p1, p2, p3;
#define TOPK_ROUND(ii, pp, FIRST)                                          \
    {                                                                      \
      float m = val;                                                       \
      m = fmaxf(m, __shfl_xor(m, 1));  m = fmaxf(m, __shfl_xor(m, 2));     \
      m = fmaxf(m, __shfl_xor(m, 4));  m = fmaxf(m, __shfl_xor(m, 8));     \
      m = fmaxf(m, __shfl_xor(m, 16)); m = fmaxf(m, __shfl_xor(m, 32));    \
      unsigned long long bm = __ballot(val == m);                          \
      int bi = (int)__builtin_ctzll(bm);                                   \
      if (FIRST) mx = m;                                                   \
      pp = expf(m - mx); wsum += pp; ii = bi;                              \
      if (tid == bi) val = -1e30f;                                         \
    }
    TOPK_ROUND(i0, p0, 1)
    TOPK_ROUND(i1, p1, 0)
    TOPK_ROUND(i2, p2, 0)
    TOPK_ROUND(i3, p3, 0)
#undef TOPK_ROUND
    if (tid == 0) {
      float inv = 1.0f / fmaxf(wsum, 1e-12f);
      topk_idx[b * 4 + 0] = i0; topk_w[b * 4 + 0] = p0 * inv;
      topk_idx[b * 4 + 1] = i1; topk_w[b * 4 + 1] = p1 * inv;
      topk_idx[b * 4 + 2] = i2; topk_w[b * 4 + 2] = p2 * inv;
      topk_idx[b * 4 + 3] = i3; topk_w[b * 4 + 3] = p3 * inv;
    }
  }
}

// ---------------- per-expert count (no atomics) ----------------
__global__ __launch_bounds__(256) void count_kernel(
    const int* __restrict__ topk_idx, int* __restrict__ counts)
{
  const int e = blockIdx.x;
  int c = 0;
  for (int i = threadIdx.x; i < NPAIR; i += 256) c += (topk_idx[i] == e);
#pragma unroll
  for (int o = 1; o < 64; o <<= 1) c += __shfl_xor(c, o);
  __shared__ int ws[4];
  if ((threadIdx.x & 63) == 0) ws[threadIdx.x >> 6] = c;
  __syncthreads();
  if (threadIdx.x == 0) counts[e] = ws[0] + ws[1] + ws[2] + ws[3];
}

__global__ void offsets_kernel(const int* __restrict__ counts, int* __restrict__ offsets) {
  if (threadIdx.x == 0) {
    int run = 0;
    for (int e = 0; e < NEXP; ++e) { offsets[e] = run; run += counts[e]; }
  }
}

// ---------------- stable scatter (deterministic, no atomics) ----------------
__global__ __launch_bounds__(256) void scatter_kernel(
    const int* __restrict__ topk_idx, const float* __restrict__ topk_w,
    const int* __restrict__ offsets,
    int* __restrict__ token_of_row, float* __restrict__ row_w)
{
  const int e = blockIdx.x;
  __shared__ int wsum[4];
  __shared__ int chunk_base;
  if (threadIdx.x == 0) chunk_base = offsets[e];
  __syncthreads();
  const int wid = threadIdx.x >> 6, lane = threadIdx.x & 63;
  for (int c0 = 0; c0 < NPAIR; c0 += 256) {
    const int t = c0 + threadIdx.x;
    const bool f = (topk_idx[t] == e);
    const unsigned long long m = __ballot(f);
    const int pre = __popcll(m & ((1ull << lane) - 1ull));
    if (lane == 0) wsum[wid] = __popcll(m);
    __syncthreads();
    int wbase = 0;
#pragma unroll
    for (int i = 0; i < 4; ++i) if (i < wid) wbase += wsum[i];
    const int total = wsum[0] + wsum[1] + wsum[2] + wsum[3];
    if (f) {
      const int pos = chunk_base + wbase + pre;
      token_of_row[pos] = t >> 2;
      row_w[pos] = topk_w[t];
    }
    __syncthreads();
    if (threadIdx.x == 0) chunk_base += total;
  }
}

// ---------------- weight transpose+convert: [E][R][C] f32 -> [E][C][R] bf16 ----------------
__global__ __launch_bounds__(256) void transpose_convert_kernel(
    const float* __restrict__ in, __hip_bfloat16* __restrict__ out, int R, int C)
{
  __shared__ float tile[32][33];
  const int e = blockIdx.z;
  const int r0 = blockIdx.y * 32, c0 = blockIdx.x * 32;
  const int x = threadIdx.x & 31, y = threadIdx.x >> 5;   // y: 0..7
  const float* ip = in + ((size_t)e * R + r0) * C + c0;
#pragma unroll
  for (int i = 0; i < 4; ++i) tile[y + 8 * i][x] = ip[(size_t)(y + 8 * i) * C + x];
  __syncthreads();
  __hip_bfloat16* op = out + ((size_t)e * C + c0) * R + r0;
#pragma unroll
  for (int i = 0; i < 4; ++i) op[(size_t)(y + 8 * i) * R + x] = __float2bfloat16(tile[x][y + 8 * i]);
}

// ================= 128x128 m97-style grouped GEMM core =================
// BM=BN=128, BK=64, 4 waves, each wave owns a 64x64 sub-tile (4x4 frags of 16x16).
// LDS layout per operand: [g:8][row:128][8 bf16], g = k/8 within the K-step.
// Staging: wave w, issue i (0..3): g = 2w + (i>>1), row = (i&1)*64 + lane.

// ---------------- GEMM1: a = relu(h @ W1 + b1), gathered rows ----------------
__global__ __launch_bounds__(256) void gemm1_kernel(
    const __hip_bfloat16* __restrict__ hb,   // [NTOK, NF]
    const __hip_bfloat16* __restrict__ W1t,  // [E, NH, NF]  (n-major)
    const float* __restrict__ b1,            // [E, NH]
    const int* __restrict__ token_of_row, const int* __restrict__ offsets,
    const int* __restrict__ counts,
    __hip_bfloat16* __restrict__ a_out)      // [NPAIR, NH]
{
  const int e  = blockIdx.z;
  const int m0 = blockIdx.y * 128;
  const int n0 = blockIdx.x * 128;
  const int cnt = counts[e];
  if (m0 >= cnt) return;
  const int off = offsets[e];

  __shared__ __align__(16) __hip_bfloat16 As[8192]; // 16 KB
  __shared__ __align__(16) __hip_bfloat16 Bs[8192];

  const int tid = threadIdx.x;
  const int w = tid >> 6, l = tid & 63;
  const int wm = w >> 1, wn = w & 1;
  const int r16 = l & 15, g4 = l >> 4;

  int rA0 = off + m0 + l;       if (rA0 > NPAIR - 1) rA0 = NPAIR - 1;
  int rA1 = off + m0 + 64 + l;  if (rA1 > NPAIR - 1) rA1 = NPAIR - 1;
  const __hip_bfloat16* Ag0 = hb + (size_t)token_of_row[rA0] * NF + 2 * w * 8;
  const __hip_bfloat16* Ag1 = hb + (size_t)token_of_row[rA1] * NF + 2 * w * 8;
  const __hip_bfloat16* Bg0 = W1t + ((size_t)e * NH + n0 + l) * NF + 2 * w * 8;
  const __hip_bfloat16* Bg1 = W1t + ((size_t)e * NH + n0 + 64 + l) * NF + 2 * w * 8;
  __hip_bfloat16* As0 = As + (2 * w) * 1024;       // g=2w, rows 0..
  __hip_bfloat16* Bs0 = Bs + (2 * w) * 1024;

  f32x4 acc[4][4] = {};

  for (int k0 = 0; k0 < NF; k0 += 64) {
    __syncthreads();
    gload16_lds(Ag0 + k0,      As0);
    gload16_lds(Ag1 + k0,      As0 + 512);
    gload16_lds(Ag0 + k0 + 8,  As0 + 1024);
    gload16_lds(Ag1 + k0 + 8,  As0 + 1536);
    gload16_lds(Bg0 + k0,      Bs0);
    gload16_lds(Bg1 + k0,      Bs0 + 512);
    gload16_lds(Bg0 + k0 + 8,  Bs0 + 1024);
    gload16_lds(Bg1 + k0 + 8,  Bs0 + 1536);
    __syncthreads();
#pragma unroll
    for (int ks = 0; ks < 2; ++ks) {
      const int g = ks * 4 + g4;
      bf16x8 af[4], bq[4];
#pragma unroll
      for (int rr = 0; rr < 4; ++rr)
        af[rr] = *(const bf16x8*)(As + (g * 128 + wm * 64 + rr * 16 + r16) * 8);
#pragma unroll
      for (int nn = 0; nn < 4; ++nn)
        bq[nn] = *(const bf16x8*)(Bs + (g * 128 + wn * 64 + nn * 16 + r16) * 8);
#pragma unroll
      for (int rr = 0; rr < 4; ++rr)
#pragma unroll
        for (int nn = 0; nn < 4; ++nn)
          acc[rr][nn] = __builtin_amdgcn_mfma_f32_16x16x32_bf16(af[rr], bq[nn], acc[rr][nn], 0, 0, 0);
    }
  }

  const int q4 = l >> 4, cl = l & 15;
  const int mmax = cnt - m0;
#pragma unroll
  for (int rr = 0; rr < 4; ++rr) {
#pragma unroll
    for (int nn = 0; nn < 4; ++nn) {
      const int c = n0 + wn * 64 + nn * 16 + cl;
      const float bias = b1[e * NH + c];
#pragma unroll
      for (int q = 0; q < 4; ++q) {
        const int r = wm * 64 + rr * 16 + q4 * 4 + q;
        if (r < mmax) {
          float v = fmaxf(acc[rr][nn][q] + bias, 0.f);
          a_out[(size_t)(off + m0 + r) * NH + c] = __float2bfloat16(v);
        }
      }
    }
  }
}

// ---------------- GEMM2: out += w * (a @ W2 + b2), fused scatter ----------------
__global__ __launch_bounds__(256) void gemm2_kernel(
    const __hip_bfloat16* __restrict__ a_in,  // [NPAIR, NH]
    const __hip_bfloat16* __restrict__ W2t,   // [E, NCOUT, NH] (n-major)
    const float* __restrict__ b2,             // [E, NCOUT]
    const int* __restrict__ token_of_row, const float* __restrict__ row_w,
    const int* __restrict__ offsets, const int* __restrict__ counts,
    float* __restrict__ out)                  // [NTOK, NCOUT]
{
  const int e  = blockIdx.z;
  const int m0 = blockIdx.y * 128;
  const int n0 = blockIdx.x * 128;
  const int cnt = counts[e];
  if (m0 >= cnt) return;
  const int off = offsets[e];

  __shared__ __align__(16) __hip_bfloat16 As[8192];
  __shared__ __align__(16) __hip_bfloat16 Bs[8192];

  const int tid = threadIdx.x;
  const int w = tid >> 6, l = tid & 63;
  const int wm = w >> 1, wn = w & 1;
  const int r16 = l & 15, g4 = l >> 4;

  int rA0 = off + m0 + l;       if (rA0 > NPAIR - 1) rA0 = NPAIR - 1;
  int rA1 = off + m0 + 64 + l;  if (rA1 > NPAIR - 1) rA1 = NPAIR - 1;
  const __hip_bfloat16* Ag0 = a_in + (size_t)rA0 * NH + 2 * w * 8;
  const __hip_bfloat16* Ag1 = a_in + (size_t)rA1 * NH + 2 * w * 8;
  const __hip_bfloat16* Bg0 = W2t + ((size_t)e * NCOUT + n0 + l) * NH + 2 * w * 8;
  const __hip_bfloat16* Bg1 = W2t + ((size_t)e * NCOUT + n0 + 64 + l) * NH + 2 * w * 8;
  __hip_bfloat16* As0 = As + (2 * w) * 1024;
  __hip_bfloat16* Bs0 = Bs + (2 * w) * 1024;

  f32x4 acc[4][4] = {};

  for (int k0 = 0; k0 < NH; k0 += 64) {
    __syncthreads();
    gload16_lds(Ag0 + k0,      As0);
    gload16_lds(Ag1 + k0,      As0 + 512);
    gload16_lds(Ag0 + k0 + 8,  As0 + 1024);
    gload16_lds(Ag1 + k0 + 8,  As0 + 1536);
    gload16_lds(Bg0 + k0,      Bs0);
    gload16_lds(Bg1 + k0,      Bs0 + 512);
    gload16_lds(Bg0 + k0 + 8,  Bs0 + 1024);
    gload16_lds(Bg1 + k0 + 8,  Bs0 + 1536);
    __syncthreads();
#pragma unroll
    for (int ks = 0; ks < 2; ++ks) {
      const int g = ks * 4 + g4;
      bf16x8 af[4], bq[4];
#pragma unroll
      for (int rr = 0; rr < 4; ++rr)
        af[rr] = *(const bf16x8*)(As + (g * 128 + wm * 64 + rr * 16 + r16) * 8);
#pragma unroll
      for (int nn = 0; nn < 4; ++nn)
        bq[nn] = *(const bf16x8*)(Bs + (g * 128 + wn * 64 + nn * 16 + r16) * 8);
#pragma unroll
      for (int rr = 0; rr < 4; ++rr)
#pragma unroll
        for (int nn = 0; nn < 4; ++nn)
          acc[rr][nn] = __builtin_amdgcn_mfma_f32_16x16x32_bf16(af[rr], bq[nn], acc[rr][nn], 0, 0, 0);
    }
  }

  const int q4 = l >> 4, cl = l & 15;
  const int mmax = cnt - m0;
#pragma unroll
  for (int rr = 0; rr < 4; ++rr) {
#pragma unroll
    for (int nn = 0; nn < 4; ++nn) {
      const int c = n0 + wn * 64 + nn * 16 + cl;
      const float bias = b2[e * NCOUT + c];
#pragma unroll
      for (int q = 0; q < 4; ++q) {
        const int r = wm * 64 + rr * 16 + q4 * 4 + q;
        if (r < mmax) {
          const int grow = off + m0 + r;
          const int tok = token_of_row[grow];
          const float wt = row_w[grow];
          atomicAdd(&out[(size_t)tok * NCOUT + c], wt * (acc[rr][nn][q] + bias));
        }
      }
    }
  }
}

extern "C" void kernel_launch(void* const* d_in, const int* in_sizes, int n_in,
                              void* d_out, int out_size, void* d_ws, size_t ws_size,
                              hipStream_t stream) {
  (void)in_sizes; (void)n_in; (void)ws_size;
  const float* h        = (const float*)d_in[0];
  const float* W_mu     = (const float*)d_in[1];
  const float* b_mu     = (const float*)d_in[2];
  const float* W_logvar = (const float*)d_in[3];
  const float* b_logvar = (const float*)d_in[4];
  const float* W1       = (const float*)d_in[5];
  const float* b1       = (const float*)d_in[6];
  const float* W2       = (const float*)d_in[7];
  const float* b2       = (const float*)d_in[8];
  float* out = (float*)d_out;

  char* p = (char*)d_ws;
  int*   counts   = (int*)p;   p += 16 * 4;
  int*   offsets  = (int*)p;   p += 16 * 4;
  float* expb     = (float*)p; p += 16 * 4;
  p += 16 * 4; // pad
  float* expW     = (float*)p; p += (size_t)NEXP * NF * 4;
  int*   topk_idx = (int*)p;   p += (size_t)NPAIR * 4;
  float* topk_w   = (float*)p; p += (size_t)NPAIR * 4;
  int*   tok_row  = (int*)p;   p += (size_t)NPAIR * 4;
  float* row_w    = (float*)p; p += (size_t)NPAIR * 4;
  __hip_bfloat16* hb   = (__hip_bfloat16*)p; p += (size_t)NTOK * NF * 2;
  __hip_bfloat16* W1t  = (__hip_bfloat16*)p; p += (size_t)NEXP * NF * NH * 2;
  __hip_bfloat16* W2t  = (__hip_bfloat16*)p; p += (size_t)NEXP * NH * NCOUT * 2;
  __hip_bfloat16* abuf = (__hip_bfloat16*)p; p += (size_t)NPAIR * NH * 2;

  hipMemsetAsync(d_out, 0, (size_t)out_size * 4, stream);

  precompute_kernel<<<(NEXP * NF + 255) / 256, 256, 0, stream>>>(W_logvar, b_logvar, expW, expb);
  router_kernel<<<NTOK, 256, 0, stream>>>(h, W_mu, b_mu, expW, expb, topk_idx, topk_w, hb);
  count_kernel<<<NEXP, 256, 0, stream>>>(topk_idx, counts);
  offsets_kernel<<<1, 64, 0, stream>>>(counts, offsets);
  scatter_kernel<<<NEXP, 256, 0, stream>>>(topk_idx, topk_w, offsets, tok_row, row_w);

  transpose_convert_kernel<<<dim3(NH / 32, NF / 32, NEXP), 256, 0, stream>>>(W1, W1t, NF, NH);
  transpose_convert_kernel<<<dim3(NCOUT / 32, NH / 32, NEXP), 256, 0, stream>>>(W2, W2t, NH, NCOUT);

  gemm1_kernel<<<dim3(NH / 128, NTOK / 128, NEXP), 256, 0, stream>>>(
      hb, W1t, b1, tok_row, offsets, counts, abuf);
  gemm2_kernel<<<dim3(NCOUT / 128, NTOK / 128, NEXP), 256, 0, stream>>>(
      abuf, W2t, b2, tok_row, row_w, offsets, counts, out);
}